// Round 2
// baseline (769.958 us; speedup 1.0000x reference)
//
#include <hip/hip_runtime.h>
#include <hip/hip_cooperative_groups.h>
#include <stdint.h>

namespace cg = cooperative_groups;

// ---------------------------------------------------------------------------
// EfficientDet post-process, single cooperative kernel + tiny init.
// Phases separated by grid.sync():
//   P0 score+hist0 -> scan0(all blocks) -> P1 hist1 -> scan1 -> P2 hist2
//   -> scan2 (threshold T) -> P3 gather -> P4 rank-sort+decode
//   -> P5 IoU bitmatrix -> P6 sequential NMS resolve + output
// ---------------------------------------------------------------------------

#define NK 1000
#define CAP 2048
#define NCLS 80
#define NW 16

typedef unsigned long long ull;

// Order-preserving float -> uint transform.
static inline __device__ unsigned fkey(float f) {
  unsigned u = __float_as_uint(f);
  return (u & 0x80000000u) ? ~u : (u | 0x80000000u);
}
static inline __device__ float fkey_inv(unsigned k) {
  unsigned u = (k & 0x80000000u) ? (k & 0x7fffffffu) : ~k;
  return __uint_as_float(u);
}

__global__ void k_init(unsigned* __restrict__ hist, unsigned* __restrict__ cand_count,
                       ull* __restrict__ cand_keys) {
  int t = blockIdx.x * blockDim.x + threadIdx.x;
  if (t < 8448) hist[t] = 0u;  // 4096 + 4096 + 256 bins
  if (t < CAP) cand_keys[t] = 0ull;
  if (t == 0) *cand_count = 0u;
}

// Redundant per-block selection scan over an nbins histogram (nbins = 256*chunk).
// Finds largest digit d with suffix-count(>=d) >= k; returns digit and the
// count strictly above it. Executed identically by every block.
__device__ __forceinline__ void scan_select(const unsigned* __restrict__ gh, int nbins,
                                            unsigned k, unsigned* s_sum, unsigned* s_res,
                                            unsigned& digit, unsigned& cum_above) {
  int t = threadIdx.x;
  int chunk = nbins >> 8;
  int base = t * chunk;
  unsigned s = 0;
  for (int b = 0; b < chunk; ++b) s += gh[base + b];
  s_sum[t] = s;
  __syncthreads();
  unsigned ca = 0;
  for (int u = t + 1; u < 256; ++u) ca += s_sum[u];
  if (ca < k && ca + s >= k) {  // exactly one thread
    unsigned cum = ca;
    for (int b = chunk - 1; b >= 0; --b) {
      unsigned c = gh[base + b];
      if (cum + c >= k) {
        s_res[0] = (unsigned)(base + b);
        s_res[1] = cum;
        break;
      }
      cum += c;
    }
  }
  __syncthreads();
  digit = s_res[0];
  cum_above = s_res[1];
  __syncthreads();
}

__global__ __launch_bounds__(256, 4) void k_main(
    const float* __restrict__ cla, const float* __restrict__ reg,
    const float* __restrict__ anchors, const int* __restrict__ hp,
    const int* __restrict__ wp, float* __restrict__ out, unsigned* __restrict__ keys,
    unsigned* __restrict__ hist, unsigned* __restrict__ cand_count,
    ull* __restrict__ cand_keys, float4* __restrict__ cand_box,
    float* __restrict__ cand_area, float* __restrict__ cand_score,
    int* __restrict__ cand_cls, int* __restrict__ cand_valid, ull* __restrict__ sup,
    int A) {
  cg::grid_group grid = cg::this_grid();
  __shared__ ull SMEM[2560];  // 20480 B, multi-purpose per phase
  __shared__ ull keep_sh[NW];
  __shared__ unsigned s_sum[256];
  __shared__ unsigned s_res[2];

  unsigned* hist0 = hist;
  unsigned* hist1 = hist + 4096;
  unsigned* hist2 = hist + 8192;

  const int t = threadIdx.x;
  const int lane = t & 63;
  const int wib = t >> 6;
  const int gwave = blockIdx.x * 4 + wib;
  const int nwaves = gridDim.x * 4;
  const int tid = blockIdx.x * 256 + t;
  const int nthr = gridDim.x * 256;

  // ---- P0: per-anchor max score -> key, + 12-bit LDS histogram ----
  unsigned* lh = (unsigned*)SMEM;
  for (int i = t; i < 4096; i += 256) lh[i] = 0u;
  __syncthreads();
  {
    const int q = lane >> 2, sub = lane & 3;  // 4 lanes per anchor row
    const int ntask = (A + 15) >> 4;          // 16 anchors per wave-task
    for (int task = gwave; task < ntask; task += nwaves) {
      int a = task * 16 + q;
      float m = -3.402823466e38f;
      if (a < A) {
        const float4* p = (const float4*)(cla + (size_t)a * NCLS);
#pragma unroll
        for (int j = 0; j < 5; ++j) {
          float4 v = p[sub + j * 4];  // quad reads 64B contiguous
          m = fmaxf(m, fmaxf(fmaxf(v.x, v.y), fmaxf(v.z, v.w)));
        }
      }
      m = fmaxf(m, __shfl_xor(m, 1, 64));
      m = fmaxf(m, __shfl_xor(m, 2, 64));
      if (sub == 0 && a < A) {
        unsigned key = fkey(m);
        keys[a] = key;
        atomicAdd(&lh[key >> 20], 1u);
      }
    }
  }
  __syncthreads();
  for (int i = t; i < 4096; i += 256) {
    unsigned c = lh[i];
    if (c) atomicAdd(&hist0[i], c);
  }
  grid.sync();

  unsigned k_rem = NK, ca;
  unsigned d0;
  scan_select(hist0, 4096, k_rem, s_sum, s_res, d0, ca);
  k_rem -= ca;

  // ---- P1: middle 12 bits ----
  for (int i = t; i < 4096; i += 256) lh[i] = 0u;
  __syncthreads();
  for (int a = tid; a < A; a += nthr) {
    unsigned key = keys[a];
    if ((key >> 20) == d0) atomicAdd(&lh[(key >> 8) & 0xFFFu], 1u);
  }
  __syncthreads();
  for (int i = t; i < 4096; i += 256) {
    unsigned c = lh[i];
    if (c) atomicAdd(&hist1[i], c);
  }
  grid.sync();

  unsigned d1;
  scan_select(hist1, 4096, k_rem, s_sum, s_res, d1, ca);
  k_rem -= ca;
  unsigned pref24 = (d0 << 12) | d1;

  // ---- P2: low 8 bits ----
  if (t < 256) lh[t] = 0u;
  __syncthreads();
  for (int a = tid; a < A; a += nthr) {
    unsigned key = keys[a];
    if ((key >> 8) == pref24) atomicAdd(&lh[key & 0xFFu], 1u);
  }
  __syncthreads();
  {
    unsigned c = lh[t];
    if (c) atomicAdd(&hist2[t], c);
  }
  grid.sync();

  unsigned d2;
  scan_select(hist2, 256, k_rem, s_sum, s_res, d2, ca);
  const unsigned T = (pref24 << 8) | d2;  // 1000th-largest key

  // ---- P3: gather all keys >= T (count >= 1000 by construction) ----
  for (int a = tid; a < A; a += nthr) {
    unsigned key = keys[a];
    if (key >= T) {
      unsigned pos = atomicAdd(cand_count, 1u);
      if (pos < CAP)
        cand_keys[pos] = ((ull)key << 32) | (ull)(~(unsigned)a);  // (score desc, idx asc)
    }
  }
  grid.sync();

  // ---- P4: rank sort (enumeration) + decode + wave argmax ----
  {
    ull* skeys = SMEM;
    for (int i = t; i < CAP; i += 256) skeys[i] = cand_keys[i];
    __syncthreads();
    float W1 = (float)wp[0] - 1.0f;
    float H1 = (float)hp[0] - 1.0f;
    for (int c = gwave; c < CAP; c += nwaves) {
      ull ck = skeys[c];
      if (ck == 0ull) continue;  // empty slot (wave-uniform)
      unsigned cnt = 0;
      for (int j = lane; j < CAP; j += 64) cnt += (skeys[j] > ck) ? 1u : 0u;
#pragma unroll
      for (int s = 1; s < 64; s <<= 1) cnt += (unsigned)__shfl_xor((int)cnt, s, 64);
      if (cnt >= NK) continue;  // rank beyond top-1000 (wave-uniform)
      int rank = (int)cnt;
      unsigned a = ~(unsigned)(ck & 0xFFFFFFFFull);
      // wave-parallel argmax over 80 classes (first-max tie rule)
      const float* row = cla + (size_t)a * NCLS;
      float v = row[lane];
      int idx = lane;
      if (lane < 16) {
        float v2 = row[64 + lane];
        if (v2 > v) { v = v2; idx = 64 + lane; }
      }
#pragma unroll
      for (int s = 1; s < 64; s <<= 1) {
        float vp = __shfl_xor(v, s, 64);
        int ip = __shfl_xor(idx, s, 64);
        if (vp > v || (vp == v && ip < idx)) { v = vp; idx = ip; }
      }
      if (lane == 0) {
        float score = fkey_inv((unsigned)(ck >> 32));
        float4 dd = ((const float4*)reg)[a];
        float4 an = ((const float4*)anchors)[a];
        float wa = an.z - an.x, ha = an.w - an.y;
        float cxa = an.x + 0.5f * wa, cya = an.y + 0.5f * ha;
        float cx = cxa + dd.x * wa, cy = cya + dd.y * ha;
        float w = wa * expf(dd.z), h = ha * expf(dd.w);
        float x1 = fminf(fmaxf(cx - 0.5f * w, 0.0f), W1);
        float y1 = fminf(fmaxf(cy - 0.5f * h, 0.0f), H1);
        float x2 = fminf(fmaxf(cx + 0.5f * w, 0.0f), W1);
        float y2 = fminf(fmaxf(cy + 0.5f * h, 0.0f), H1);
        cand_box[rank] = make_float4(x1, y1, x2, y2);
        cand_area[rank] = fmaxf(x2 - x1, 0.0f) * fmaxf(y2 - y1, 0.0f);
        cand_score[rank] = score;
        cand_cls[rank] = idx;
        cand_valid[rank] = (score > 0.5f) ? 1 : 0;
      }
    }
  }
  grid.sync();

  // ---- P5: 1000x1000 IoU>0.5 bitmatrix (blocks 0..62) ----
  if (blockIdx.x < 63) {
    float4* sbox = (float4*)SMEM;
    float* sarea = (float*)((char*)SMEM + sizeof(float4) * NK);
    for (int i = t; i < NK; i += 256) {
      sbox[i] = cand_box[i];
      sarea[i] = cand_area[i];
    }
    __syncthreads();
    int g = blockIdx.x * 256 + t;
    int i = g >> 4, w = g & 15;
    if (i < NK) {
      float4 bi = sbox[i];
      float ai = sarea[i];
      ull bits = 0ull;
      int j0 = w * 64;
      int jend = (j0 + 64 < NK) ? (j0 + 64) : NK;
      for (int j = j0; j < jend; ++j) {
        float4 bj = sbox[j];
        float xx1 = fmaxf(bi.x, bj.x), yy1 = fmaxf(bi.y, bj.y);
        float xx2 = fminf(bi.z, bj.z), yy2 = fminf(bi.w, bj.w);
        float inter = fmaxf(xx2 - xx1, 0.0f) * fmaxf(yy2 - yy1, 0.0f);
        float uni = ai + sarea[j] - inter;
        float iou = inter / fmaxf(uni, 1e-8f);
        if (iou > 0.5f) bits |= (1ull << (j - j0));
      }
      sup[(size_t)i * NW + w] = bits;
    }
  }
  grid.sync();

  // ---- P6: sequential NMS resolve (block 0 wave 0) + output ----
  if (blockIdx.x == 0) {
    if (t < 64) {
      ull keepw[NW];
#pragma unroll
      for (int c = 0; c < NW; ++c) {
        int row = c * 64 + lane;
        ull rw[NW];
        int vld = 0;
        if (row < NK) {
#pragma unroll
          for (int w = 0; w < NW; ++w) rw[w] = sup[(size_t)row * NW + w];
          vld = cand_valid[row];
        } else {
#pragma unroll
          for (int w = 0; w < NW; ++w) rw[w] = 0ull;
        }
        ull prev = 0ull;
#pragma unroll
        for (int w = 0; w < NW; ++w)
          if (w < c) prev |= rw[w] & keepw[w];
        int flags = (vld ? 2 : 0) | ((prev != 0ull) ? 1 : 0);
        unsigned Llo = (unsigned)rw[c];
        unsigned Lhi = (unsigned)(rw[c] >> 32);
        ull kept = 0ull;
        for (int b = 0; b < 64; ++b) {
          int fb = __shfl(flags, b, 64);
          unsigned lo = (unsigned)__shfl((int)Llo, b, 64);
          unsigned hi = (unsigned)__shfl((int)Lhi, b, 64);
          ull Lb = ((ull)hi << 32) | (ull)lo;
          bool kp = ((fb & 2) != 0) && ((fb & 1) == 0) && ((Lb & kept) == 0ull);
          kept |= ((ull)(kp ? 1u : 0u)) << b;
        }
        keepw[c] = kept;
      }
      if (lane == 0) {
#pragma unroll
        for (int w = 0; w < NW; ++w) keep_sh[w] = keepw[w];
      }
    }
    __syncthreads();
    for (int i = t; i < NK; i += 256) {
      bool kp = (keep_sh[i >> 6] >> (i & 63)) & 1ull;
      out[i] = kp ? cand_score[i] : 0.0f;
      out[NK + i] = kp ? (float)cand_cls[i] : -1.0f;  // int output read as float
      float4 b = cand_box[i];
      ((float4*)(out + 2 * NK))[i] = kp ? b : make_float4(0.f, 0.f, 0.f, 0.f);
    }
  }
}

extern "C" void kernel_launch(void* const* d_in, const int* in_sizes, int n_in,
                              void* d_out, int out_size, void* d_ws, size_t ws_size,
                              hipStream_t stream) {
  const float* cla = (const float*)d_in[0];
  const float* reg = (const float*)d_in[1];
  const float* anchors = (const float*)d_in[2];
  const int* hp = (const int*)d_in[3];
  const int* wp = (const int*)d_in[4];
  float* out = (float*)d_out;
  int A = in_sizes[2] / 4;  // 441936

  char* ws = (char*)d_ws;
  size_t off = 0;
  auto carve = [&](size_t bytes) -> void* {
    void* p = ws + off;
    off += bytes;
    off = (off + 255) & ~(size_t)255;
    return p;
  };
  unsigned* keys = (unsigned*)carve((size_t)A * 4);
  unsigned* hist = (unsigned*)carve(8448 * 4);
  unsigned* cand_count = (unsigned*)carve(4);
  ull* cand_keys = (ull*)carve(CAP * 8);
  float4* cand_box = (float4*)carve(1024 * 16);
  float* cand_area = (float*)carve(1024 * 4);
  float* cand_score = (float*)carve(1024 * 4);
  int* cand_cls = (int*)carve(1024 * 4);
  int* cand_valid = (int*)carve(1024 * 4);
  ull* sup = (ull*)carve((size_t)1024 * NW * 8);
  (void)ws_size;
  (void)n_in;
  (void)out_size;

  k_init<<<33, 256, 0, stream>>>(hist, cand_count, cand_keys);

  int maxb = 0;
  hipOccupancyMaxActiveBlocksPerMultiprocessor(&maxb, k_main, 256, 0);
  if (maxb < 1) maxb = 1;
  int grid = maxb * 256;  // 256 CUs on MI355X
  if (grid > 1024) grid = 1024;
  if (grid < 64) grid = 64;

  void* args[] = {&cla,        &reg,       &anchors,   &hp,       &wp,       &out,
                  &keys,       &hist,      &cand_count, &cand_keys, &cand_box, &cand_area,
                  &cand_score, &cand_cls,  &cand_valid, &sup,      &A};
  hipLaunchCooperativeKernel(k_main, dim3(grid), dim3(256), args, 0, stream);
}

// Round 3
// 356.304 us; speedup vs baseline: 2.1610x; 2.1610x over previous
//
#include <hip/hip_runtime.h>
#include <stdint.h>

// ---------------------------------------------------------------------------
// EfficientDet post-process, multi-dispatch (grid.sync() proved ~100us/sync on
// 8-XCD gfx950 in round 2 -> kernel-boundary sync instead).
// Dispatches: memset(zero hist/count/cand_keys) ->
//   k_score   : per-anchor max over 80 classes -> key + 12-bit global hist0
//   k_hist1   : redundant scan(hist0) per block, middle-12-bit hist1
//   k_hist2   : scans(hist0,hist1), low-8-bit hist2
//   k_gather  : scans(all), threshold T, per-block-aggregated gather
//   k_rankdec : per-thread rank sort of 2048 keys + decode + argmax class
//   k_supmat  : 1000x1000 IoU>0.5 bitmatrix
//   k_resolve : chunked-wave sequential NMS + output write
// ---------------------------------------------------------------------------

#define NK 1000
#define CAP 2048
#define NCLS 80
#define NW 16
typedef unsigned long long ull;

static inline __device__ unsigned fkey(float f) {
  unsigned u = __float_as_uint(f);
  return (u & 0x80000000u) ? ~u : (u | 0x80000000u);
}
static inline __device__ float fkey_inv(unsigned k) {
  unsigned u = (k & 0x80000000u) ? (k & 0x7fffffffu) : ~k;
  return __uint_as_float(u);
}

// Redundant per-block selection scan (blockDim must be 256). Finds largest
// digit with suffix-count >= k and the count strictly above that digit.
__device__ __forceinline__ void scan_select(const unsigned* __restrict__ gh, int nbins,
                                            unsigned k, unsigned* s_sum, unsigned* s_res,
                                            unsigned& digit, unsigned& cum_above) {
  int t = threadIdx.x;
  int chunk = nbins >> 8;
  int base = t * chunk;
  unsigned s = 0;
  for (int b = 0; b < chunk; ++b) s += gh[base + b];
  s_sum[t] = s;
  __syncthreads();
  unsigned ca = 0;
  for (int u = t + 1; u < 256; ++u) ca += s_sum[u];
  if (ca < k && ca + s >= k) {  // exactly one thread
    unsigned cum = ca;
    for (int b = chunk - 1; b >= 0; --b) {
      unsigned c = gh[base + b];
      if (cum + c >= k) { s_res[0] = (unsigned)(base + b); s_res[1] = cum; break; }
      cum += c;
    }
  }
  __syncthreads();
  digit = s_res[0];
  cum_above = s_res[1];
  __syncthreads();
}

// ---- K1: score + key + top-12-bit histogram --------------------------------
__global__ __launch_bounds__(256) void k_score(const float* __restrict__ cla,
                                               unsigned* __restrict__ keys,
                                               unsigned* __restrict__ hist0, int A) {
  __shared__ unsigned lh[4096];
  int t = threadIdx.x;
  for (int i = t; i < 4096; i += 256) lh[i] = 0u;
  __syncthreads();
  const int lane = t & 63, wib = t >> 6;
  const int gwave = blockIdx.x * 4 + wib, nwaves = gridDim.x * 4;
  const int q = lane >> 2, sub = lane & 3;  // 4 lanes per 320B anchor row
  const int ntask = (A + 15) >> 4;
  for (int task = gwave; task < ntask; task += nwaves) {
    int a = task * 16 + q;
    float m = -3.402823466e38f;
    if (a < A) {
      const float4* p = (const float4*)(cla + (size_t)a * NCLS);
#pragma unroll
      for (int j = 0; j < 5; ++j) {
        float4 v = p[sub + j * 4];
        m = fmaxf(m, fmaxf(fmaxf(v.x, v.y), fmaxf(v.z, v.w)));
      }
    }
    m = fmaxf(m, __shfl_xor(m, 1, 64));
    m = fmaxf(m, __shfl_xor(m, 2, 64));
    if (sub == 0 && a < A) {
      unsigned key = fkey(m);
      keys[a] = key;
      atomicAdd(&lh[key >> 20], 1u);
    }
  }
  __syncthreads();
  for (int i = t; i < 4096; i += 256) {
    unsigned c = lh[i];
    if (c) atomicAdd(&hist0[i], c);
  }
}

// ---- K2: middle-12-bit histogram -------------------------------------------
__global__ __launch_bounds__(256) void k_hist1(const unsigned* __restrict__ keys,
                                               const unsigned* __restrict__ hist0,
                                               unsigned* __restrict__ hist1, int A) {
  __shared__ unsigned lh[4096];
  __shared__ unsigned s_sum[256];
  __shared__ unsigned s_res[2];
  int t = threadIdx.x;
  unsigned d0, ca;
  scan_select(hist0, 4096, NK, s_sum, s_res, d0, ca);
  for (int i = t; i < 4096; i += 256) lh[i] = 0u;
  __syncthreads();
  int tid = blockIdx.x * 256 + t, nthr = gridDim.x * 256;
  for (int a = tid; a < A; a += nthr) {
    unsigned key = keys[a];
    if ((key >> 20) == d0) atomicAdd(&lh[(key >> 8) & 0xFFFu], 1u);
  }
  __syncthreads();
  for (int i = t; i < 4096; i += 256) {
    unsigned c = lh[i];
    if (c) atomicAdd(&hist1[i], c);
  }
}

// ---- K3: low-8-bit histogram -----------------------------------------------
__global__ __launch_bounds__(256) void k_hist2(const unsigned* __restrict__ keys,
                                               const unsigned* __restrict__ hist0,
                                               const unsigned* __restrict__ hist1,
                                               unsigned* __restrict__ hist2, int A) {
  __shared__ unsigned lh[256];
  __shared__ unsigned s_sum[256];
  __shared__ unsigned s_res[2];
  int t = threadIdx.x;
  unsigned k_rem = NK, d0, d1, ca;
  scan_select(hist0, 4096, k_rem, s_sum, s_res, d0, ca);
  k_rem -= ca;
  scan_select(hist1, 4096, k_rem, s_sum, s_res, d1, ca);
  unsigned pref24 = (d0 << 12) | d1;
  lh[t] = 0u;
  __syncthreads();
  int tid = blockIdx.x * 256 + t, nthr = gridDim.x * 256;
  for (int a = tid; a < A; a += nthr) {
    unsigned key = keys[a];
    if ((key >> 8) == pref24) atomicAdd(&lh[key & 0xFFu], 1u);
  }
  __syncthreads();
  unsigned c = lh[t];
  if (c) atomicAdd(&hist2[t], c);
}

// ---- K4: threshold + gather (per-block LDS aggregation) --------------------
__global__ __launch_bounds__(256) void k_gather(const unsigned* __restrict__ keys,
                                                const unsigned* __restrict__ hist0,
                                                const unsigned* __restrict__ hist1,
                                                const unsigned* __restrict__ hist2,
                                                unsigned* __restrict__ cand_count,
                                                ull* __restrict__ cand_keys, int A) {
  __shared__ unsigned s_sum[256];
  __shared__ unsigned s_res[2];
  __shared__ ull lbuf[1024];
  __shared__ unsigned lcnt;
  __shared__ unsigned gbase;
  int t = threadIdx.x;
  unsigned k_rem = NK, d0, d1, d2, ca;
  scan_select(hist0, 4096, k_rem, s_sum, s_res, d0, ca);
  k_rem -= ca;
  scan_select(hist1, 4096, k_rem, s_sum, s_res, d1, ca);
  k_rem -= ca;
  scan_select(hist2, 256, k_rem, s_sum, s_res, d2, ca);
  const unsigned T = (((d0 << 12) | d1) << 8) | d2;  // 1000th-largest key
  if (t == 0) lcnt = 0u;
  __syncthreads();
  int tid = blockIdx.x * 256 + t, nthr = gridDim.x * 256;
  for (int a = tid; a < A; a += nthr) {
    unsigned key = keys[a];
    if (key >= T) {
      unsigned pos = atomicAdd(&lcnt, 1u);
      if (pos < 1024)
        lbuf[pos] = ((ull)key << 32) | (ull)(~(unsigned)a);  // (score desc, idx asc)
    }
  }
  __syncthreads();
  if (t == 0) gbase = (lcnt > 0) ? atomicAdd(cand_count, lcnt) : 0u;
  __syncthreads();
  unsigned n = lcnt < 1024u ? lcnt : 1024u;
  for (unsigned i = t; i < n; i += 256) {
    unsigned pos = gbase + i;
    if (pos < CAP) cand_keys[pos] = lbuf[i];
  }
}

// ---- K5: rank sort + decode + argmax class ---------------------------------
__global__ __launch_bounds__(256) void k_rankdec(
    const float* __restrict__ cla, const float* __restrict__ reg,
    const float* __restrict__ anchors, const int* __restrict__ hp,
    const int* __restrict__ wp, const ull* __restrict__ cand_keys,
    float4* __restrict__ cand_box, float* __restrict__ cand_area,
    float* __restrict__ cand_score, int* __restrict__ cand_cls,
    int* __restrict__ cand_valid) {
  __shared__ ull skeys[CAP];
  int t = threadIdx.x;
  for (int i = t; i < CAP; i += 256) skeys[i] = cand_keys[i];
  __syncthreads();
  int c = blockIdx.x * 256 + t;  // 8 blocks x 256 = CAP
  ull ck = skeys[c];
  if (ck == 0ull) return;  // empty slot
  unsigned cnt = 0;
  const ulonglong2* sk2 = (const ulonglong2*)skeys;
#pragma unroll 4
  for (int j = 0; j < CAP / 2; ++j) {
    ulonglong2 v = sk2[j];
    cnt += (v.x > ck) ? 1u : 0u;
    cnt += (v.y > ck) ? 1u : 0u;
  }
  if (cnt >= NK) return;  // beyond top-1000
  int rank = (int)cnt;
  unsigned a = ~(unsigned)(ck & 0xFFFFFFFFull);
  float score = fkey_inv((unsigned)(ck >> 32));
  float W1 = (float)wp[0] - 1.0f;
  float H1 = (float)hp[0] - 1.0f;
  float4 dd = ((const float4*)reg)[a];
  float4 an = ((const float4*)anchors)[a];
  float wa = an.z - an.x, ha = an.w - an.y;
  float cxa = an.x + 0.5f * wa, cya = an.y + 0.5f * ha;
  float cx = cxa + dd.x * wa, cy = cya + dd.y * ha;
  float w = wa * expf(dd.z), h = ha * expf(dd.w);
  float x1 = fminf(fmaxf(cx - 0.5f * w, 0.0f), W1);
  float y1 = fminf(fmaxf(cy - 0.5f * h, 0.0f), H1);
  float x2 = fminf(fmaxf(cx + 0.5f * w, 0.0f), W1);
  float y2 = fminf(fmaxf(cy + 0.5f * h, 0.0f), H1);
  cand_box[rank] = make_float4(x1, y1, x2, y2);
  cand_area[rank] = fmaxf(x2 - x1, 0.0f) * fmaxf(y2 - y1, 0.0f);
  cand_score[rank] = score;
  cand_valid[rank] = (score > 0.5f) ? 1 : 0;
  // per-thread argmax over 80 classes (first-max tie rule)
  const float* row = cla + (size_t)a * NCLS;
  float m = -3.402823466e38f;
  int ci = 0;
#pragma unroll
  for (int j = 0; j < NCLS; ++j) {
    float v = row[j];
    if (v > m) { m = v; ci = j; }
  }
  cand_cls[rank] = ci;
}

// ---- K6: 1000x1000 IoU>0.5 bitmatrix ---------------------------------------
__global__ __launch_bounds__(256) void k_supmat(const float4* __restrict__ cand_box,
                                                const float* __restrict__ cand_area,
                                                ull* __restrict__ sup) {
  __shared__ float4 bx[NK];
  __shared__ float ar[NK];
  int t = threadIdx.x;
  for (int i = t; i < NK; i += 256) {
    bx[i] = cand_box[i];
    ar[i] = cand_area[i];
  }
  __syncthreads();
  int g = blockIdx.x * 256 + t;
  int i = g >> 4, w = g & 15;
  if (i >= NK) return;
  float4 bi = bx[i];
  float ai = ar[i];
  ull bits = 0ull;
  int j0 = w * 64;
  int jend = (j0 + 64 < NK) ? (j0 + 64) : NK;
  for (int j = j0; j < jend; ++j) {
    float4 bj = bx[j];
    float xx1 = fmaxf(bi.x, bj.x), yy1 = fmaxf(bi.y, bj.y);
    float xx2 = fminf(bi.z, bj.z), yy2 = fminf(bi.w, bj.w);
    float inter = fmaxf(xx2 - xx1, 0.0f) * fmaxf(yy2 - yy1, 0.0f);
    float uni = ai + ar[j] - inter;
    float iou = inter / fmaxf(uni, 1e-8f);
    if (iou > 0.5f) bits |= (1ull << (j - j0));
  }
  sup[(size_t)i * NW + w] = bits;
}

// ---- K7: sequential NMS resolve + output -----------------------------------
__global__ __launch_bounds__(1024) void k_resolve(const ull* __restrict__ sup,
                                                  const int* __restrict__ cand_valid,
                                                  const float* __restrict__ cand_score,
                                                  const int* __restrict__ cand_cls,
                                                  const float4* __restrict__ cand_box,
                                                  float* __restrict__ out) {
  __shared__ ull keep_sh[NW];
  int t = threadIdx.x;
  if (t < 64) {
    int lane = t;
    ull keepw[NW];
#pragma unroll
    for (int c = 0; c < NW; ++c) {
      int row = c * 64 + lane;
      ull rw[NW];
      int vld = 0;
      if (row < NK) {
#pragma unroll
        for (int w = 0; w < NW; ++w) rw[w] = sup[(size_t)row * NW + w];
        vld = cand_valid[row];
      } else {
#pragma unroll
        for (int w = 0; w < NW; ++w) rw[w] = 0ull;
      }
      ull prev = 0ull;
#pragma unroll
      for (int w = 0; w < NW; ++w)
        if (w < c) prev |= rw[w] & keepw[w];
      int flags = (vld ? 2 : 0) | ((prev != 0ull) ? 1 : 0);
      unsigned Llo = (unsigned)rw[c];
      unsigned Lhi = (unsigned)(rw[c] >> 32);
      ull kept = 0ull;
      for (int b = 0; b < 64; ++b) {
        int fb = __shfl(flags, b, 64);
        unsigned lo = (unsigned)__shfl((int)Llo, b, 64);
        unsigned hi = (unsigned)__shfl((int)Lhi, b, 64);
        ull Lb = ((ull)hi << 32) | (ull)lo;
        bool kp = ((fb & 2) != 0) && ((fb & 1) == 0) && ((Lb & kept) == 0ull);
        kept |= ((ull)(kp ? 1u : 0u)) << b;
      }
      keepw[c] = kept;
    }
    if (lane == 0) {
#pragma unroll
      for (int w = 0; w < NW; ++w) keep_sh[w] = keepw[w];
    }
  }
  __syncthreads();
  for (int i = t; i < NK; i += 1024) {
    bool kp = (keep_sh[i >> 6] >> (i & 63)) & 1ull;
    out[i] = kp ? cand_score[i] : 0.0f;
    out[NK + i] = kp ? (float)cand_cls[i] : -1.0f;  // int output read as float
    float4 b = cand_box[i];
    ((float4*)(out + 2 * NK))[i] = kp ? b : make_float4(0.f, 0.f, 0.f, 0.f);
  }
}

extern "C" void kernel_launch(void* const* d_in, const int* in_sizes, int n_in,
                              void* d_out, int out_size, void* d_ws, size_t ws_size,
                              hipStream_t stream) {
  const float* cla = (const float*)d_in[0];
  const float* reg = (const float*)d_in[1];
  const float* anchors = (const float*)d_in[2];
  const int* hp = (const int*)d_in[3];
  const int* wp = (const int*)d_in[4];
  float* out = (float*)d_out;
  int A = in_sizes[2] / 4;  // 441936

  char* ws = (char*)d_ws;
  size_t off = 0;
  auto carve = [&](size_t bytes) -> void* {
    void* p = ws + off;
    off += bytes;
    off = (off + 255) & ~(size_t)255;
    return p;
  };
  unsigned* keys = (unsigned*)carve((size_t)A * 4);
  // contiguous zero-init region: hist0|hist1|hist2|cand_count|cand_keys
  char* zbase = ws + off;
  unsigned* hist0 = (unsigned*)carve(4096 * 4);
  unsigned* hist1 = (unsigned*)carve(4096 * 4);
  unsigned* hist2 = (unsigned*)carve(256 * 4);
  unsigned* cand_count = (unsigned*)carve(4);
  ull* cand_keys = (ull*)carve(CAP * 8);
  size_t zbytes = (size_t)((ws + off) - zbase);
  float4* cand_box = (float4*)carve(1024 * 16);
  float* cand_area = (float*)carve(1024 * 4);
  float* cand_score = (float*)carve(1024 * 4);
  int* cand_cls = (int*)carve(1024 * 4);
  int* cand_valid = (int*)carve(1024 * 4);
  ull* sup = (ull*)carve((size_t)1024 * NW * 8);
  (void)ws_size;
  (void)n_in;
  (void)out_size;

  hipMemsetAsync(zbase, 0, zbytes, stream);
  k_score<<<1024, 256, 0, stream>>>(cla, keys, hist0, A);
  k_hist1<<<512, 256, 0, stream>>>(keys, hist0, hist1, A);
  k_hist2<<<512, 256, 0, stream>>>(keys, hist0, hist1, hist2, A);
  k_gather<<<512, 256, 0, stream>>>(keys, hist0, hist1, hist2, cand_count, cand_keys, A);
  k_rankdec<<<8, 256, 0, stream>>>(cla, reg, anchors, hp, wp, cand_keys, cand_box,
                                   cand_area, cand_score, cand_cls, cand_valid);
  k_supmat<<<63, 256, 0, stream>>>(cand_box, cand_area, sup);
  k_resolve<<<1, 1024, 0, stream>>>(sup, cand_valid, cand_score, cand_cls, cand_box, out);
}